// Round 2
// baseline (424.258 us; speedup 1.0000x reference)
//
#include <hip/hip_runtime.h>

#define NN 4096
#define DIN 64
#define DOUTC 16
#define CCH 4
#define K_TOT (NN*CCH)        // 16384
#define N_OUT (DOUTC*CCH)     // 64
#define SPLITS 16
#define KRANGE (K_TOT/SPLITS) // 1024 k per block

typedef __bf16 bf16x8 __attribute__((ext_vector_type(8)));
typedef __bf16 bf16x4 __attribute__((ext_vector_type(4)));
typedef float  f32x4  __attribute__((ext_vector_type(4)));

// ---------------- kernel 1: build Bt [64][16384] bf16 ----------------
// Bt[(r*4+c)][(j*4+cp)] = S[j][r][(c-cp)&3]
// where S[j][r][cc] = sum_d sum_cp' feat[j][d][cp'] * w[d][r][(cc-cp')&3]
__global__ void support_kernel(const float* __restrict__ feat,  // [4096][64][4]
                               const float* __restrict__ wgt,   // [64][16][4]
                               __bf16* __restrict__ Bt) {
    const int t  = threadIdx.x;
    const int r  = t & 15;
    const int jl = t >> 4;                 // 0..15
    const int j  = blockIdx.x * 16 + jl;

    float a0 = 0.f, a1 = 0.f, a2 = 0.f, a3 = 0.f;
    const f32x4* f4 = (const f32x4*)(feat + (size_t)j * DIN * CCH);
    const f32x4* w4 = (const f32x4*)wgt;
    #pragma unroll 8
    for (int d = 0; d < DIN; ++d) {
        f32x4 f = f4[d];
        f32x4 w = w4[d * 16 + r];
        a0 += f[0]*w[0] + f[1]*w[3] + f[2]*w[2] + f[3]*w[1];
        a1 += f[0]*w[1] + f[1]*w[0] + f[2]*w[3] + f[3]*w[2];
        a2 += f[0]*w[2] + f[1]*w[1] + f[2]*w[0] + f[3]*w[3];
        a3 += f[0]*w[3] + f[1]*w[2] + f[2]*w[1] + f[3]*w[0];
    }
    float accs[4] = {a0, a1, a2, a3};
    // row n = r*4+c gets [accs[(c-0)&3], accs[(c-1)&3], accs[(c-2)&3], accs[(c-3)&3]]
    #pragma unroll
    for (int c = 0; c < 4; ++c) {
        bf16x4 b;
        b[0] = (__bf16)accs[c];
        b[1] = (__bf16)accs[(c + 3) & 3];
        b[2] = (__bf16)accs[(c + 2) & 3];
        b[3] = (__bf16)accs[(c + 1) & 3];
        *(bf16x4*)(Bt + (size_t)(r * 4 + c) * K_TOT + j * 4) = b;
    }
}

// ---------------- kernel 2: part[split] = adj x Bt^T (no LDS, no barriers) ----------------
// Each wave owns 16 rows and a 1024-wide K range; fragments loaded directly
// from global (A: f32->bf16 on the fly; B: bf16 from L2-resident Bt).
__launch_bounds__(256)
__global__ void gemm_kernel(const float* __restrict__ A,    // adj, [4096][16384] f32
                            const __bf16* __restrict__ Bt,  // [64][16384] bf16
                            float* __restrict__ part) {     // [SPLITS][4096][64] f32
    const int t    = threadIdx.x;
    const int wave = t >> 6;
    const int lane = t & 63;
    const int row  = blockIdx.x * 64 + wave * 16 + (lane & 15);
    const int kq   = lane >> 4;           // 0..3
    const int kbase = blockIdx.y * KRANGE;

    const float*  Ap = A  + (size_t)row * K_TOT + kbase + kq * 8;
    const __bf16* Bp = Bt + (size_t)(lane & 15) * K_TOT + kbase + kq * 8;

    f32x4 acc[4] = {};

    #pragma unroll 2
    for (int ks = 0; ks < KRANGE / 32; ++ks) {
        f32x4 a0 = *(const f32x4*)(Ap + ks * 32);
        f32x4 a1 = *(const f32x4*)(Ap + ks * 32 + 4);
        bf16x8 af;
        af[0] = (__bf16)a0[0]; af[1] = (__bf16)a0[1];
        af[2] = (__bf16)a0[2]; af[3] = (__bf16)a0[3];
        af[4] = (__bf16)a1[0]; af[5] = (__bf16)a1[1];
        af[6] = (__bf16)a1[2]; af[7] = (__bf16)a1[3];
        #pragma unroll
        for (int nf = 0; nf < 4; ++nf) {
            bf16x8 bf = *(const bf16x8*)(Bp + (size_t)nf * 16 * K_TOT + ks * 32);
            acc[nf] = __builtin_amdgcn_mfma_f32_16x16x32_bf16(af, bf, acc[nf], 0, 0, 0);
        }
    }

    // store partials (plain coalesced-ish stores, no atomics)
    const int col  = lane & 15;
    const int rowg = lane >> 4;
    float* P = part + ((size_t)blockIdx.y * NN + blockIdx.x * 64 + wave * 16) * N_OUT;
    #pragma unroll
    for (int nf = 0; nf < 4; ++nf) {
        #pragma unroll
        for (int e = 0; e < 4; ++e) {
            P[(rowg * 4 + e) * N_OUT + nf * 16 + col] = acc[nf][e];
        }
    }
}

// ---------------- kernel 3: out = bias + sum_s part[s] ----------------
__global__ void reduce_kernel(const float* __restrict__ part,
                              const float* __restrict__ bias,
                              float* __restrict__ out) {
    int t = blockIdx.x * blockDim.x + threadIdx.x;   // 0..65535 (f32x4 units)
    f32x4 s = ((const f32x4*)bias)[t];
    #pragma unroll
    for (int sp = 0; sp < SPLITS; ++sp) {
        s += ((const f32x4*)(part + (size_t)sp * NN * N_OUT))[t];
    }
    ((f32x4*)out)[t] = s;
}

extern "C" void kernel_launch(void* const* d_in, const int* in_sizes, int n_in,
                              void* d_out, int out_size, void* d_ws, size_t ws_size,
                              hipStream_t stream) {
    const float* feat = (const float*)d_in[0];  // [4096][64][4]
    const float* adj  = (const float*)d_in[1];  // [4096][4096][4]
    const float* wgt  = (const float*)d_in[2];  // [64][16][4]
    const float* bias = (const float*)d_in[3];  // [4096][16][4]
    float* out = (float*)d_out;                 // [4096][16][4]

    float*  part = (float*)d_ws;                             // 16 MB
    __bf16* Bt   = (__bf16*)((char*)d_ws + (size_t)SPLITS * NN * N_OUT * 4);  // 2 MB

    support_kernel<<<NN / 16, 256, 0, stream>>>(feat, wgt, Bt);
    dim3 grid(NN / 64, SPLITS);
    gemm_kernel<<<grid, 256, 0, stream>>>(adj, Bt, part);
    reduce_kernel<<<NN * N_OUT / 4 / 256, 256, 0, stream>>>(part, bias, out);
}